// Round 9
// baseline (341.519 us; speedup 1.0000x reference)
//
#include <hip/hip_runtime.h>
#include <cmath>

// CRSDCell bf16-MFMA pipeline, round 9: k_fused BM=64 (halve weight L2 traffic
// + per-step overhead per output). Full panels staged once (sR 64K + sX 32K),
// 24+16 barrier-free K-steps, h_norm overlays sR for GEMM2.
//  - 8 n-waves x 64 cols; per wave 2 row-subtiles (mi) x 2 col-subtiles (ni).
//  - Weights pre-packed chunk-major P[k0][slot4][n][8]; B-frags global->VGPR
//    one step ahead (L2-resident).
//  - k_rk (BM=32, fused r_seq + k/q partials) unchanged from round 8.
// FFT folds exactly: irfft(rfft(h)*s) = s*h. h_prev=r_prev=0 kills Wh/A terms.

typedef __attribute__((ext_vector_type(8)))  short short8;
typedef __attribute__((ext_vector_type(16))) float f32x16;

__device__ __forceinline__ unsigned short f2bf(float f) {
  union { float f; unsigned u; } v; v.f = f;
  unsigned r = v.u + 0x7FFF + ((v.u >> 16) & 1);   // RTNE
  return (unsigned short)(r >> 16);
}
__device__ __forceinline__ float bf2f(unsigned short h) {
  union { unsigned u; float f; } v; v.u = ((unsigned)h) << 16; return v.f;
}
__device__ __forceinline__ f32x16 mfma16(short8 a, short8 b, f32x16 c) {
  return __builtin_amdgcn_mfma_f32_32x32x16_bf16(a, b, c, 0, 0, 0);
}
__device__ __forceinline__ void barrier_lgkm() {
  asm volatile("s_waitcnt lgkmcnt(0)" ::: "memory");
  __builtin_amdgcn_s_barrier();
  __builtin_amdgcn_sched_barrier(0);
}

// ---------------- weight convert + pack ----------------
// packed offset for (n,k) in [N][K]: (k>>5)*N*32 + ((k>>3)&3)*N*8 + n*8 + (k&7)
__global__ __launch_bounds__(256) void k_wconv(
    const float* __restrict__ wx, const float* __restrict__ key,
    const float* __restrict__ bw, const float* __restrict__ uw,
    const float* __restrict__ fftpw, const float* __restrict__ fg,
    unsigned short* __restrict__ wxp, unsigned short* __restrict__ keyp,
    unsigned short* __restrict__ bwp, unsigned short* __restrict__ uwp,
    unsigned short* __restrict__ fftps) {
  int i = blockIdx.x * 256 + threadIdx.x;
  if (i >= 884736) return;
  float v; int n, k, N; unsigned short* dst;
  if (i < 131072)      { int j = i;          N = 512; k = j & 255; n = j >> 8; v = wx[j];  dst = wxp; }
  else if (i < 229376) { int j = i - 131072; N = 128; k = j % 768; n = j / 768; v = key[j]; dst = keyp; }
  else if (i < 491520) { int j = i - 229376; N = 512; k = j & 511; n = j >> 9; v = bw[j];  dst = bwp; }
  else if (i < 622592) { int j = i - 491520; N = 512; k = j & 255; n = j >> 8; v = uw[j];  dst = uwp; }
  else                 { int j = i - 622592; N = 512; k = j & 511; n = j >> 9; v = fftpw[j] * fg[k]; dst = fftps; }
  dst[(k >> 5) * (N * 32) + ((k >> 3) & 3) * (N * 8) + n * 8 + (k & 7)] = f2bf(v);
}

// ---------------- K_RK: r_seq + k/q partials (BM=32) ----------------
__global__ __launch_bounds__(512, 4) void k_rk(
    const float* __restrict__ x, const unsigned short* __restrict__ wxp,
    const unsigned short* __restrict__ keyp,
    const float* __restrict__ wxb, const float* __restrict__ resa,
    const float* __restrict__ rng, const float* __restrict__ rnb,
    const float* __restrict__ keyb,
    float* __restrict__ rout, float* __restrict__ partial) {
  __shared__ short sX[8192];    // x panel  32x256 bf16 (16KB)
  __shared__ short sR[16384];   // r panel  32x512 bf16 (32KB); kp overlays later
  __shared__ float red[640];
  const int t = threadIdx.x, w = t >> 6, lane = t & 63, lr = lane & 31, lh = lane >> 5;
  const int m0 = blockIdx.x * 32;

  // ---- stage x panel ----
#pragma unroll
  for (int i = 0; i < 4; ++i) {
    int c = t + i * 512;                 // float4 idx; 64 per row
    int row = c >> 6, k0 = (c & 63) * 4;
    float4 v = *reinterpret_cast<const float4*>(x + (size_t)(m0 + row) * 256 + k0);
    uint2 p;
    p.x = (unsigned)f2bf(v.x) | ((unsigned)f2bf(v.y) << 16);
    p.y = (unsigned)f2bf(v.z) | ((unsigned)f2bf(v.w) << 16);
    *reinterpret_cast<uint2*>(&sX[(k0 >> 3) * 256 + row * 8 + (k0 & 7)]) = p;
  }
  barrier_lgkm();

  // ---- GEMM0: r_pre = x @ Wx^T, 8 barrier-free steps ----
  f32x16 acc[2];
#pragma unroll
  for (int ni = 0; ni < 2; ++ni)
#pragma unroll
    for (int e = 0; e < 16; ++e) acc[ni][e] = 0.f;
  short8 b0[4], b1[4];
  auto loadB0 = [&](int s, short8 (&bd)[4]) {
#pragma unroll
    for (int kh = 0; kh < 2; ++kh)
#pragma unroll
      for (int ni = 0; ni < 2; ++ni)
        bd[kh * 2 + ni] = *reinterpret_cast<const short8*>(
            wxp + (size_t)s * 16384 + (kh * 2 + lh) * 4096 + (64 * w + 32 * ni + lr) * 8);
  };
  auto mf0 = [&](int s, short8 (&bc)[4]) {
    short8 af[2];
#pragma unroll
    for (int kh = 0; kh < 2; ++kh)
      af[kh] = *reinterpret_cast<const short8*>(&sX[(s * 4 + kh * 2 + lh) * 256 + lr * 8]);
    __builtin_amdgcn_s_setprio(1);
#pragma unroll
    for (int kh = 0; kh < 2; ++kh)
#pragma unroll
      for (int ni = 0; ni < 2; ++ni)
        acc[ni] = mfma16(af[kh], bc[kh * 2 + ni], acc[ni]);
    __builtin_amdgcn_s_setprio(0);
  };
  loadB0(0, b0);
  for (int s = 0; s < 8; s += 2) {
    loadB0(s + 1, b1);
    mf0(s, b0);
    if (s + 2 < 8) loadB0(s + 2, b0);
    mf0(s + 1, b1);
  }

  // ---- epi0: z=(1-a)tanh(.+b), LN, write rout + sR ----
#pragma unroll
  for (int ni = 0; ni < 2; ++ni) {
    int col = 64 * w + 32 * ni + lr;
    float al = 1.f / (1.f + expf(-resa[col >> 7]));
    float oma = 1.f - al, bbv = wxb[col];
#pragma unroll
    for (int r = 0; r < 16; ++r)
      acc[ni][r] = oma * tanhf(acc[ni][r] + bbv);
  }
#pragma unroll
  for (int r = 0; r < 16; ++r) {
    float s1 = acc[0][r] + acc[1][r];
    float s2 = acc[0][r] * acc[0][r] + acc[1][r] * acc[1][r];
#pragma unroll
    for (int m = 1; m <= 16; m <<= 1) { s1 += __shfl_xor(s1, m); s2 += __shfl_xor(s2, m); }
    int rl = (r & 3) + 8 * (r >> 2) + 4 * lh;
    if (lr == r) { red[w * 32 + rl] = s1; red[256 + w * 32 + rl] = s2; }
  }
  __syncthreads();
  if (t < 32) {
    float s1 = 0.f, s2 = 0.f;
#pragma unroll
    for (int n = 0; n < 8; ++n) { s1 += red[n * 32 + t]; s2 += red[256 + n * 32 + t]; }
    float mean = s1 * (1.f / 512.f);
    float var = s2 * (1.f / 512.f) - mean * mean;
    float rstd = rsqrtf(var + 1e-5f);
    red[512 + t * 2] = mean;
    red[512 + t * 2 + 1] = rstd;
  }
  __syncthreads();
#pragma unroll
  for (int q = 0; q < 4; ++q) {
    float4 stA = *reinterpret_cast<float4*>(&red[512 + (8 * q + 4 * lh) * 2]);
    float4 stB = *reinterpret_cast<float4*>(&red[512 + (8 * q + 4 * lh) * 2 + 4]);
    float mean[4] = {stA.x, stA.z, stB.x, stB.z};
    float rstd[4] = {stA.y, stA.w, stB.y, stB.w};
#pragma unroll
    for (int ni = 0; ni < 2; ++ni) {
      int col = 64 * w + 32 * ni + lr;
      float g = rng[col], bbv = rnb[col];
#pragma unroll
      for (int e = 0; e < 4; ++e) {
        int r = 4 * q + e;
        int rloc = 8 * q + 4 * lh + e;
        float val = (acc[ni][r] - mean[e]) * rstd[e] * g + bbv;
        rout[(size_t)(m0 + rloc) * 512 + col] = val;
        sR[(col >> 3) * 256 + rloc * 8 + (col & 7)] = (short)f2bf(val);
      }
    }
  }
  barrier_lgkm();

  // ---- GEMM_k: k = [r,x] @ key^T, split-K over 2 wave-groups ----
  const int g = w >> 2, nw2 = w & 3;     // group, wave-in-group (32 cols each)
  f32x16 ak;
#pragma unroll
  for (int e = 0; e < 16; ++e) ak[e] = 0.f;
  short8 kb0[2], kb1[2];
  auto loadBk = [&](int gc, short8 (&bd)[2]) {
#pragma unroll
    for (int kh = 0; kh < 2; ++kh)
      bd[kh] = *reinterpret_cast<const short8*>(
          keyp + (size_t)gc * 4096 + (kh * 2 + lh) * 1024 + (32 * nw2 + lr) * 8);
  };
  auto mfk = [&](int gc, short8 (&bc)[2]) {
    const short* P = (gc < 16) ? sR : sX;
    int sb = (gc < 16) ? gc * 4 : (gc - 16) * 4;
    short8 af[2];
#pragma unroll
    for (int kh = 0; kh < 2; ++kh)
      af[kh] = *reinterpret_cast<const short8*>(&P[(sb + kh * 2 + lh) * 256 + lr * 8]);
    __builtin_amdgcn_s_setprio(1);
#pragma unroll
    for (int kh = 0; kh < 2; ++kh)
      ak = mfma16(af[kh], bc[kh], ak);
    __builtin_amdgcn_s_setprio(0);
  };
  const int gbase = g * 12;
  loadBk(gbase, kb0);
  for (int s = 0; s < 12; s += 2) {
    loadBk(gbase + s + 1, kb1);
    mfk(gbase + s, kb0);
    if (s + 2 < 12) loadBk(gbase + s + 2, kb0);
    mfk(gbase + s + 1, kb1);
  }
  __syncthreads();                        // all sR/sX reads done
  float* kp = reinterpret_cast<float*>(sR);  // kp[g][32 rows][128 cols]
#pragma unroll
  for (int r = 0; r < 16; ++r) {
    int rr = (r & 3) + 8 * (r >> 2) + 4 * lh;
    kp[g * 4096 + rr * 128 + nw2 * 32 + lr] = ak[r];
  }
  __syncthreads();
  // pass1: per-row sumsq -> scale
  {
    int rr = t >> 4, cg = t & 15;
    float s1 = 0.f;
#pragma unroll
    for (int j = 0; j < 8; ++j) {
      int c = cg * 8 + j;
      float v = kp[rr * 128 + c] + kp[4096 + rr * 128 + c] + keyb[c];
      s1 += v * v;
    }
#pragma unroll
    for (int m = 1; m <= 8; m <<= 1) s1 += __shfl_xor(s1, m);
    if (cg == 0) red[rr] = 1.f / fmaxf(sqrtf(s1), 1e-8f);
  }
  __syncthreads();
  // pass2: column partials of l2norm(k)
  if (t < 128) {
    float p = 0.f;
    float bb = keyb[t];
#pragma unroll 4
    for (int rr = 0; rr < 32; ++rr)
      p += (kp[rr * 128 + t] + kp[4096 + rr * 128 + t] + bb) * red[rr];
    partial[(size_t)blockIdx.x * 128 + t] = p;
  }
}

// ---------------- q reduce (2048 partial blocks, 256 per batch) -------------
__global__ __launch_bounds__(256) void k_qred(const float* __restrict__ partial,
                                              float* __restrict__ q_ws) {
  int gid = blockIdx.x * 256 + threadIdx.x;   // 0..1023
  int b = gid >> 7, c = gid & 127;
  float s = 0.f;
  for (int i = 0; i < 256; ++i) s += partial[(size_t)(b * 256 + i) * 128 + c];
  q_ws[gid] = s * (1.f / 8192.f);
}

// ---------------- cvec = fftn_b @ fftp_w^T (raw fftp) ----------------
__global__ __launch_bounds__(256) void k_cvec(const float* __restrict__ fb,
                                              const float* __restrict__ fftpw,
                                              float* __restrict__ cvec) {
  int o = blockIdx.x * 256 + threadIdx.x;     // 0..511
  const float* w = fftpw + (size_t)o * 512;
  float s = 0.f;
  for (int k = 0; k < 512; ++k) s += fb[k] * w[k];
  cvec[o] = s;
}

// ---------------- memory (episodic + hebbian) ----------------
__global__ __launch_bounds__(256) void k_mem(
    const float* __restrict__ q_ws, const float* __restrict__ mkeys,
    const float* __restrict__ mvals, const float* __restrict__ hebH,
    const float* __restrict__ rmw, const float* __restrict__ rmb,
    const float* __restrict__ mixl, float* __restrict__ hm) {
  const int b = blockIdx.x, t = threadIdx.x;
  __shared__ float qv[128];
  __shared__ float ssim[256];
  __shared__ float red[256];
  __shared__ float tval[8];
  __shared__ int tidx[8];
  __shared__ float wsm[8];
  __shared__ float vcs[128];

  if (t < 128) qv[t] = q_ws[b * 128 + t];
  __syncthreads();
  red[t] = (t < 128) ? qv[t] * qv[t] : 0.f;
  __syncthreads();
  for (int s = 128; s > 0; s >>= 1) {
    if (t < s) red[t] += red[t + s];
    __syncthreads();
  }
  float qsc = 1.f / fmaxf(sqrtf(red[0]), 1e-8f);
  {
    const float* mk = mkeys + ((size_t)b * 256 + t) * 128;
    float dot = 0.f, ms = 0.f;
    for (int k = 0; k < 128; ++k) { float mv = mk[k]; dot += qv[k] * mv; ms += mv * mv; }
    ssim[t] = dot * qsc / fmaxf(sqrtf(ms), 1e-8f);
  }
  __syncthreads();
  for (int it = 0; it < 8; ++it) {
    if (t < 64) {
      float bv = -1e30f; int bi = 0;
#pragma unroll
      for (int u = 0; u < 4; ++u) {
        int m = t * 4 + u;
        float v = ssim[m];
        if (v > bv) { bv = v; bi = m; }
      }
      for (int off = 32; off; off >>= 1) {
        float ov = __shfl_xor(bv, off, 64);
        int oi = __shfl_xor(bi, off, 64);
        if (ov > bv || (ov == bv && oi < bi)) { bv = ov; bi = oi; }
      }
      if (t == 0) { tval[it] = bv; tidx[it] = bi; ssim[bi] = -1e30f; }
    }
    __syncthreads();
  }
  if (t == 0) {
    float m0 = tval[0], sum = 0.f, e[8];
#pragma unroll
    for (int i = 0; i < 8; ++i) { e[i] = expf(tval[i] - m0); sum += e[i]; }
#pragma unroll
    for (int i = 0; i < 8; ++i) wsm[i] = e[i] / sum;
  }
  __syncthreads();
  float mix = 1.f / (1.f + expf(-mixl[0]));
  if (t < 128) {
    float vh = 0.f;
#pragma unroll
    for (int i = 0; i < 8; ++i) vh += wsm[i] * mvals[((size_t)b * 256 + tidx[i]) * 128 + t];
    float vhb = 0.f;
    const float* H = hebH + (size_t)b * 128 * 128;
    for (int k = 0; k < 128; ++k) vhb += qv[k] * H[k * 128 + t];
    vcs[t] = mix * vh + (1.f - mix) * vhb;
  }
  __syncthreads();
  for (int h = t; h < 512; h += 256) {
    float sum = rmb[h];
    const float* wr = rmw + (size_t)h * 128;
    for (int v = 0; v < 128; ++v) sum += vcs[v] * wr[v];
    hm[b * 512 + h] = sum;
  }
}

// ---------------- fused h_tilde -> LN -> fftp GEMM -> hs (BM=64) ------------
// LDS: sR 64K (h_norm overlays) + sX 32K + red 4.5K = ~101KB, 1 block/CU.
__global__ __launch_bounds__(512, 2) void k_fused(
    const float* __restrict__ rseq, const float* __restrict__ x,
    const unsigned short* __restrict__ bwp, const unsigned short* __restrict__ uwp,
    const float* __restrict__ ub, const unsigned short* __restrict__ fftps,
    const float* __restrict__ fftpb, const float* __restrict__ fmix,
    const float* __restrict__ cvec, const float* __restrict__ hm,
    float* __restrict__ hs) {
  __shared__ short sR[32768];   // r panel 64x512 [(k>>3)][row64][8]; h_norm overlays
  __shared__ short sX[16384];   // x panel 64x256 [(k>>3)][row64][8]
  __shared__ float red[1152];
  const int t = threadIdx.x, w = t >> 6, lane = t & 63, lr = lane & 31, lh = lane >> 5;
  const int m0 = blockIdx.x * 64;
  const int bidx = m0 >> 13;

  // ---- stage r panel (16 f4/thread) + x panel (8 f4/thread) ----
#pragma unroll
  for (int i = 0; i < 16; ++i) {
    int c = t + i * 512;                 // 128 float4 per row
    int row = c >> 7, k0 = (c & 127) * 4;
    float4 v = *reinterpret_cast<const float4*>(rseq + (size_t)(m0 + row) * 512 + k0);
    uint2 p;
    p.x = (unsigned)f2bf(v.x) | ((unsigned)f2bf(v.y) << 16);
    p.y = (unsigned)f2bf(v.z) | ((unsigned)f2bf(v.w) << 16);
    *reinterpret_cast<uint2*>(&sR[(k0 >> 3) * 512 + row * 8 + (k0 & 7)]) = p;
  }
#pragma unroll
  for (int i = 0; i < 8; ++i) {
    int c = t + i * 512;                 // 64 float4 per row
    int row = c >> 6, k0 = (c & 63) * 4;
    float4 v = *reinterpret_cast<const float4*>(x + (size_t)(m0 + row) * 256 + k0);
    uint2 p;
    p.x = (unsigned)f2bf(v.x) | ((unsigned)f2bf(v.y) << 16);
    p.y = (unsigned)f2bf(v.z) | ((unsigned)f2bf(v.w) << 16);
    *reinterpret_cast<uint2*>(&sX[(k0 >> 3) * 512 + row * 8 + (k0 & 7)]) = p;
  }
  barrier_lgkm();

  // ---- GEMM1: h_pre = [r,x] @ [Bw,Uw]^T, 24 barrier-free steps ----
  f32x16 acc[2][2];
#pragma unroll
  for (int mi = 0; mi < 2; ++mi)
#pragma unroll
    for (int ni = 0; ni < 2; ++ni)
#pragma unroll
      for (int e = 0; e < 16; ++e) acc[mi][ni][e] = 0.f;
  short8 b0[4], b1[4];
  auto loadB1 = [&](int s, short8 (&bd)[4]) {
    const unsigned short* wp = (s < 16) ? (bwp + (size_t)s * 16384)
                                        : (uwp + (size_t)(s - 16) * 16384);
#pragma unroll
    for (int kh = 0; kh < 2; ++kh)
#pragma unroll
      for (int ni = 0; ni < 2; ++ni)
        bd[kh * 2 + ni] = *reinterpret_cast<const short8*>(
            wp + (kh * 2 + lh) * 4096 + (64 * w + 32 * ni + lr) * 8);
  };
  auto mf1 = [&](int s, short8 (&bc)[4]) {
    const short* P = (s < 16) ? sR : sX;
    int sb = (s < 16) ? s * 4 : (s - 16) * 4;
    short8 af[2][2];
#pragma unroll
    for (int kh = 0; kh < 2; ++kh)
#pragma unroll
      for (int mi = 0; mi < 2; ++mi)
        af[kh][mi] = *reinterpret_cast<const short8*>(
            &P[(sb + kh * 2 + lh) * 512 + (32 * mi + lr) * 8]);
    __builtin_amdgcn_s_setprio(1);
#pragma unroll
    for (int kh = 0; kh < 2; ++kh)
#pragma unroll
      for (int mi = 0; mi < 2; ++mi)
#pragma unroll
        for (int ni = 0; ni < 2; ++ni)
          acc[mi][ni] = mfma16(af[kh][mi], bc[kh * 2 + ni], acc[mi][ni]);
    __builtin_amdgcn_s_setprio(0);
  };
  loadB1(0, b0);
  for (int s = 0; s < 24; s += 2) {
    loadB1(s + 1, b1);
    mf1(s, b0);
    if (s + 2 < 24) loadB1(s + 2, b0);
    mf1(s + 1, b1);
  }

  // ---- epi1: gelu, LN stats (64 rows), pack h~, write h_norm into sR ----
#pragma unroll
  for (int mi = 0; mi < 2; ++mi)
#pragma unroll
    for (int ni = 0; ni < 2; ++ni) {
      int col = 64 * w + 32 * ni + lr;
      float ubc = ub[col];
#pragma unroll
      for (int r = 0; r < 16; ++r) {
        float pre = acc[mi][ni][r] + ubc;
        acc[mi][ni][r] = 0.5f * pre * (1.f + erff(pre * 0.70710678118654752f));
      }
    }
#pragma unroll
  for (int mi = 0; mi < 2; ++mi)
#pragma unroll
    for (int r = 0; r < 16; ++r) {
      float s1 = acc[mi][0][r] + acc[mi][1][r];
      float s2 = acc[mi][0][r] * acc[mi][0][r] + acc[mi][1][r] * acc[mi][1][r];
#pragma unroll
      for (int m = 1; m <= 16; m <<= 1) { s1 += __shfl_xor(s1, m); s2 += __shfl_xor(s2, m); }
      int rl = (r & 3) + 8 * (r >> 2) + 4 * lh;
      if (lr == r) { red[(w * 2 + mi) * 32 + rl] = s1; red[512 + (w * 2 + mi) * 32 + rl] = s2; }
    }
  __syncthreads();                       // all GEMM1 sR reads done
  if (t < 64) {
    int mi = t >> 5, rl = t & 31;
    float s1 = 0.f, s2 = 0.f;
#pragma unroll
    for (int n = 0; n < 8; ++n) { s1 += red[(n * 2 + mi) * 32 + rl]; s2 += red[512 + (n * 2 + mi) * 32 + rl]; }
    float mean = s1 * (1.f / 512.f);
    float var = s2 * (1.f / 512.f) - mean * mean;
    float rstd = rsqrtf(var + 1e-5f);
    red[1024 + t * 2] = mean;
    red[1024 + t * 2 + 1] = rstd;
  }
  __syncthreads();
  unsigned htp[2][2][8];
#pragma unroll
  for (int mi = 0; mi < 2; ++mi)
#pragma unroll
    for (int ni = 0; ni < 2; ++ni)
#pragma unroll
      for (int p = 0; p < 8; ++p)
        htp[mi][ni][p] = (unsigned)f2bf(acc[mi][ni][2 * p]) |
                         ((unsigned)f2bf(acc[mi][ni][2 * p + 1]) << 16);
  auto loadB2 = [&](int s, short8 (&bd)[4]) {
#pragma unroll
    for (int kh = 0; kh < 2; ++kh)
#pragma unroll
      for (int ni = 0; ni < 2; ++ni)
        bd[kh * 2 + ni] = *reinterpret_cast<const short8*>(
            fftps + (size_t)s * 16384 + (kh * 2 + lh) * 4096 + (64 * w + 32 * ni + lr) * 8);
  };
  loadB2(0, b0);                         // prefetch under h_norm writes
#pragma unroll
  for (int q = 0; q < 4; ++q)
#pragma unroll
    for (int mi = 0; mi < 2; ++mi) {
      float4 stA = *reinterpret_cast<float4*>(&red[1024 + (32 * mi + 8 * q + 4 * lh) * 2]);
      float4 stB = *reinterpret_cast<float4*>(&red[1024 + (32 * mi + 8 * q + 4 * lh) * 2 + 4]);
      float mean[4] = {stA.x, stA.z, stB.x, stB.z};
      float rstd[4] = {stA.y, stA.w, stB.y, stB.w};
#pragma unroll
      for (int ni = 0; ni < 2; ++ni) {
        int col = 64 * w + 32 * ni + lr;
#pragma unroll
        for (int e = 0; e < 4; ++e) {
          int r = 4 * q + e;
          float z = (acc[mi][ni][r] - mean[e]) * rstd[e];
          int rloc = 32 * mi + 8 * q + 4 * lh + e;
          sR[(col >> 3) * 512 + rloc * 8 + (col & 7)] = (short)f2bf(z);
        }
      }
    }
#pragma unroll
  for (int mi = 0; mi < 2; ++mi)
#pragma unroll
    for (int ni = 0; ni < 2; ++ni)
#pragma unroll
      for (int e = 0; e < 16; ++e) acc[mi][ni][e] = 0.f;
  barrier_lgkm();

  // ---- GEMM2: h_norm @ (fftp*g)^T, 16 barrier-free steps ----
  auto mf2 = [&](int s, short8 (&bc)[4]) {
    short8 af[2][2];
#pragma unroll
    for (int kh = 0; kh < 2; ++kh)
#pragma unroll
      for (int mi = 0; mi < 2; ++mi)
        af[kh][mi] = *reinterpret_cast<const short8*>(
            &sR[(s * 4 + kh * 2 + lh) * 512 + (32 * mi + lr) * 8]);
    __builtin_amdgcn_s_setprio(1);
#pragma unroll
    for (int kh = 0; kh < 2; ++kh)
#pragma unroll
      for (int mi = 0; mi < 2; ++mi)
#pragma unroll
        for (int ni = 0; ni < 2; ++ni)
          acc[mi][ni] = mfma16(af[kh][mi], bc[kh * 2 + ni], acc[mi][ni]);
    __builtin_amdgcn_s_setprio(0);
  };
  for (int s = 0; s < 16; s += 2) {
    loadB2(s + 1, b1);
    mf2(s, b0);
    if (s + 2 < 16) loadB2(s + 2, b0);
    mf2(s + 1, b1);
  }

  // ---- epi2: combine ----
  const float sg = 1.f / (1.f + expf(-fmix[0]));
  const float s2f = sg * sg, oms = 1.f - sg;
#pragma unroll
  for (int mi = 0; mi < 2; ++mi)
#pragma unroll
    for (int ni = 0; ni < 2; ++ni) {
      int col = 64 * w + 32 * ni + lr;
      float base = s2f * cvec[col] + sg * fftpb[col] + 0.5f * hm[bidx * 512 + col];
#pragma unroll
      for (int p = 0; p < 8; ++p) {
        unsigned pk = htp[mi][ni][p];
        int r0 = 2 * p;
        int rloc = 32 * mi + (r0 & 3) + 8 * (r0 >> 2) + 4 * lh;
        float o0 = oms * bf2f((unsigned short)(pk & 0xFFFF)) + s2f * acc[mi][ni][r0] + base;
        float o1 = oms * bf2f((unsigned short)(pk >> 16)) + s2f * acc[mi][ni][r0 + 1] + base;
        hs[(size_t)(m0 + rloc) * 512 + col] = o0;
        hs[(size_t)(m0 + rloc + 1) * 512 + col] = o1;
      }
    }
}

extern "C" void kernel_launch(void* const* d_in, const int* in_sizes, int n_in,
                              void* d_out, int out_size, void* d_ws, size_t ws_size,
                              hipStream_t stream) {
  (void)in_sizes; (void)n_in; (void)out_size; (void)ws_size;
  const float* x     = (const float*)d_in[0];
  const float* Wxw   = (const float*)d_in[1];
  const float* Wxb   = (const float*)d_in[2];
  const float* resa  = (const float*)d_in[4];
  const float* Bw    = (const float*)d_in[6];
  const float* Uw    = (const float*)d_in[7];
  const float* Ub    = (const float*)d_in[8];
  const float* fg    = (const float*)d_in[9];
  const float* fb    = (const float*)d_in[10];
  const float* fftpw = (const float*)d_in[11];
  const float* fftpb = (const float*)d_in[12];
  const float* fmix  = (const float*)d_in[13];
  const float* mixl  = (const float*)d_in[14];
  const float* keyw  = (const float*)d_in[15];
  const float* keyb  = (const float*)d_in[16];
  const float* rmw   = (const float*)d_in[19];
  const float* rmb   = (const float*)d_in[20];
  const float* rng   = (const float*)d_in[21];
  const float* rnb   = (const float*)d_in[22];
  const float* mkeys = (const float*)d_in[23];
  const float* mvals = (const float*)d_in[24];
  const float* hebH  = (const float*)d_in[25];

  float* outp = (float*)d_out;
  float* hs   = outp;                               // (B,T,512)
  float* rout = outp + (size_t)65536 * 512;         // (B,T,512)

  unsigned short* wsu = (unsigned short*)d_ws;
  unsigned short* wxp    = wsu;                     // 131072
  unsigned short* keyp   = wsu + 131072;            // 98304
  unsigned short* bwp    = wsu + 229376;            // 262144
  unsigned short* uwp    = wsu + 491520;            // 131072
  unsigned short* fftps  = wsu + 622592;            // 262144
  float* wsf     = (float*)d_ws;
  float* partial = wsf + 524288;                    // 2048*128 = 262144
  float* q_ws    = wsf + 786432;                    // 1024
  float* hm      = wsf + 787456;                    // 4096
  float* cvec    = wsf + 791552;                    // 512

  k_wconv<<<3456, 256, 0, stream>>>(Wxw, keyw, Bw, Uw, fftpw, fg,
                                    wxp, keyp, bwp, uwp, fftps);
  k_cvec <<<2,    256, 0, stream>>>(fb, fftpw, cvec);
  k_rk   <<<2048, 512, 0, stream>>>(x, wxp, keyp, Wxb, resa, rng, rnb, keyb,
                                    rout, partial);
  k_qred <<<4,    256, 0, stream>>>(partial, q_ws);
  k_mem  <<<8,    256, 0, stream>>>(q_ws, mkeys, mvals, hebH, rmw, rmb, mixl, hm);
  k_fused<<<1024, 512, 0, stream>>>(rout, x, bwp, uwp, Ub, fftps, fftpb,
                                    fmix, cvec, hm, hs);
}

// Round 10
// 334.018 us; speedup vs baseline: 1.0225x; 1.0225x over previous
//
#include <hip/hip_runtime.h>
#include <cmath>

// CRSDCell bf16-MFMA pipeline, round 10: revert k_fused to BM=32 (round-8,
// 42% occ) + DEPTH-2 register B-prefetch (3-buffer static rotation) in all
// GEMM loops — covers ~2 steps of L2 latency instead of 1.
//  - Panels staged once (k-slot layout, conflict-free); GEMM K-loops
//    barrier-free; weights pre-packed chunk-major P[k0][slot4][n][8].
//  - k_rk: fused r_seq + k/q partials (BM=32, split-K k-GEMM).
// FFT folds exactly: irfft(rfft(h)*s) = s*h. h_prev=r_prev=0 kills Wh/A terms.

typedef __attribute__((ext_vector_type(8)))  short short8;
typedef __attribute__((ext_vector_type(16))) float f32x16;

__device__ __forceinline__ unsigned short f2bf(float f) {
  union { float f; unsigned u; } v; v.f = f;
  unsigned r = v.u + 0x7FFF + ((v.u >> 16) & 1);   // RTNE
  return (unsigned short)(r >> 16);
}
__device__ __forceinline__ float bf2f(unsigned short h) {
  union { unsigned u; float f; } v; v.u = ((unsigned)h) << 16; return v.f;
}
__device__ __forceinline__ f32x16 mfma16(short8 a, short8 b, f32x16 c) {
  return __builtin_amdgcn_mfma_f32_32x32x16_bf16(a, b, c, 0, 0, 0);
}
__device__ __forceinline__ void barrier_lgkm() {
  asm volatile("s_waitcnt lgkmcnt(0)" ::: "memory");
  __builtin_amdgcn_s_barrier();
  __builtin_amdgcn_sched_barrier(0);
}

// ---------------- weight convert + pack ----------------
// packed offset for (n,k) in [N][K]: (k>>5)*N*32 + ((k>>3)&3)*N*8 + n*8 + (k&7)
__global__ __launch_bounds__(256) void k_wconv(
    const float* __restrict__ wx, const float* __restrict__ key,
    const float* __restrict__ bw, const float* __restrict__ uw,
    const float* __restrict__ fftpw, const float* __restrict__ fg,
    unsigned short* __restrict__ wxp, unsigned short* __restrict__ keyp,
    unsigned short* __restrict__ bwp, unsigned short* __restrict__ uwp,
    unsigned short* __restrict__ fftps) {
  int i = blockIdx.x * 256 + threadIdx.x;
  if (i >= 884736) return;
  float v; int n, k, N; unsigned short* dst;
  if (i < 131072)      { int j = i;          N = 512; k = j & 255; n = j >> 8; v = wx[j];  dst = wxp; }
  else if (i < 229376) { int j = i - 131072; N = 128; k = j % 768; n = j / 768; v = key[j]; dst = keyp; }
  else if (i < 491520) { int j = i - 229376; N = 512; k = j & 511; n = j >> 9; v = bw[j];  dst = bwp; }
  else if (i < 622592) { int j = i - 491520; N = 512; k = j & 255; n = j >> 8; v = uw[j];  dst = uwp; }
  else                 { int j = i - 622592; N = 512; k = j & 511; n = j >> 9; v = fftpw[j] * fg[k]; dst = fftps; }
  dst[(k >> 5) * (N * 32) + ((k >> 3) & 3) * (N * 8) + n * 8 + (k & 7)] = f2bf(v);
}

// ---------------- K_RK: r_seq + k/q partials (BM=32) ----------------
__global__ __launch_bounds__(512, 4) void k_rk(
    const float* __restrict__ x, const unsigned short* __restrict__ wxp,
    const unsigned short* __restrict__ keyp,
    const float* __restrict__ wxb, const float* __restrict__ resa,
    const float* __restrict__ rng, const float* __restrict__ rnb,
    const float* __restrict__ keyb,
    float* __restrict__ rout, float* __restrict__ partial) {
  __shared__ short sX[8192];    // x panel  32x256 bf16 (16KB)
  __shared__ short sR[16384];   // r panel  32x512 bf16 (32KB); kp overlays later
  __shared__ float red[640];
  const int t = threadIdx.x, w = t >> 6, lane = t & 63, lr = lane & 31, lh = lane >> 5;
  const int m0 = blockIdx.x * 32;

  // ---- stage x panel ----
#pragma unroll
  for (int i = 0; i < 4; ++i) {
    int c = t + i * 512;                 // float4 idx; 64 per row
    int row = c >> 6, k0 = (c & 63) * 4;
    float4 v = *reinterpret_cast<const float4*>(x + (size_t)(m0 + row) * 256 + k0);
    uint2 p;
    p.x = (unsigned)f2bf(v.x) | ((unsigned)f2bf(v.y) << 16);
    p.y = (unsigned)f2bf(v.z) | ((unsigned)f2bf(v.w) << 16);
    *reinterpret_cast<uint2*>(&sX[(k0 >> 3) * 256 + row * 8 + (k0 & 7)]) = p;
  }
  barrier_lgkm();

  // ---- GEMM0: r_pre = x @ Wx^T, 8 barrier-free steps, depth-2 prefetch ----
  f32x16 acc[2];
#pragma unroll
  for (int ni = 0; ni < 2; ++ni)
#pragma unroll
    for (int e = 0; e < 16; ++e) acc[ni][e] = 0.f;
  short8 b0[4], b1[4], b2[4];
  auto loadB0 = [&](int s, short8 (&bd)[4]) {
#pragma unroll
    for (int kh = 0; kh < 2; ++kh)
#pragma unroll
      for (int ni = 0; ni < 2; ++ni)
        bd[kh * 2 + ni] = *reinterpret_cast<const short8*>(
            wxp + (size_t)s * 16384 + (kh * 2 + lh) * 4096 + (64 * w + 32 * ni + lr) * 8);
  };
  auto mf0 = [&](int s, short8 (&bc)[4]) {
    short8 af[2];
#pragma unroll
    for (int kh = 0; kh < 2; ++kh)
      af[kh] = *reinterpret_cast<const short8*>(&sX[(s * 4 + kh * 2 + lh) * 256 + lr * 8]);
    __builtin_amdgcn_s_setprio(1);
#pragma unroll
    for (int kh = 0; kh < 2; ++kh)
#pragma unroll
      for (int ni = 0; ni < 2; ++ni)
        acc[ni] = mfma16(af[kh], bc[kh * 2 + ni], acc[ni]);
    __builtin_amdgcn_s_setprio(0);
  };
  loadB0(0, b0);
  loadB0(1, b1);
  for (int s = 0; s < 6; s += 3) {
    loadB0(s + 2, b2); mf0(s, b0);
    loadB0(s + 3, b0); mf0(s + 1, b1);
    loadB0(s + 4, b1); mf0(s + 2, b2);
  }
  mf0(6, b0);
  mf0(7, b1);

  // ---- epi0: z=(1-a)tanh(.+b), LN, write rout + sR ----
#pragma unroll
  for (int ni = 0; ni < 2; ++ni) {
    int col = 64 * w + 32 * ni + lr;
    float al = 1.f / (1.f + expf(-resa[col >> 7]));
    float oma = 1.f - al, bbv = wxb[col];
#pragma unroll
    for (int r = 0; r < 16; ++r)
      acc[ni][r] = oma * tanhf(acc[ni][r] + bbv);
  }
#pragma unroll
  for (int r = 0; r < 16; ++r) {
    float s1 = acc[0][r] + acc[1][r];
    float s2 = acc[0][r] * acc[0][r] + acc[1][r] * acc[1][r];
#pragma unroll
    for (int m = 1; m <= 16; m <<= 1) { s1 += __shfl_xor(s1, m); s2 += __shfl_xor(s2, m); }
    int rl = (r & 3) + 8 * (r >> 2) + 4 * lh;
    if (lr == r) { red[w * 32 + rl] = s1; red[256 + w * 32 + rl] = s2; }
  }
  __syncthreads();
  if (t < 32) {
    float s1 = 0.f, s2 = 0.f;
#pragma unroll
    for (int n = 0; n < 8; ++n) { s1 += red[n * 32 + t]; s2 += red[256 + n * 32 + t]; }
    float mean = s1 * (1.f / 512.f);
    float var = s2 * (1.f / 512.f) - mean * mean;
    float rstd = rsqrtf(var + 1e-5f);
    red[512 + t * 2] = mean;
    red[512 + t * 2 + 1] = rstd;
  }
  __syncthreads();
#pragma unroll
  for (int q = 0; q < 4; ++q) {
    float4 stA = *reinterpret_cast<float4*>(&red[512 + (8 * q + 4 * lh) * 2]);
    float4 stB = *reinterpret_cast<float4*>(&red[512 + (8 * q + 4 * lh) * 2 + 4]);
    float mean[4] = {stA.x, stA.z, stB.x, stB.z};
    float rstd[4] = {stA.y, stA.w, stB.y, stB.w};
#pragma unroll
    for (int ni = 0; ni < 2; ++ni) {
      int col = 64 * w + 32 * ni + lr;
      float g = rng[col], bbv = rnb[col];
#pragma unroll
      for (int e = 0; e < 4; ++e) {
        int r = 4 * q + e;
        int rloc = 8 * q + 4 * lh + e;
        float val = (acc[ni][r] - mean[e]) * rstd[e] * g + bbv;
        rout[(size_t)(m0 + rloc) * 512 + col] = val;
        sR[(col >> 3) * 256 + rloc * 8 + (col & 7)] = (short)f2bf(val);
      }
    }
  }
  barrier_lgkm();

  // ---- GEMM_k: k = [r,x] @ key^T, split-K over 2 wave-groups, depth-2 ----
  const int g = w >> 2, nw2 = w & 3;     // group, wave-in-group (32 cols each)
  f32x16 ak;
#pragma unroll
  for (int e = 0; e < 16; ++e) ak[e] = 0.f;
  short8 kb0[2], kb1[2], kb2[2];
  auto loadBk = [&](int gc, short8 (&bd)[2]) {
#pragma unroll
    for (int kh = 0; kh < 2; ++kh)
      bd[kh] = *reinterpret_cast<const short8*>(
          keyp + (size_t)gc * 4096 + (kh * 2 + lh) * 1024 + (32 * nw2 + lr) * 8);
  };
  auto mfk = [&](int gc, short8 (&bc)[2]) {
    const short* P = (gc < 16) ? sR : sX;
    int sb = (gc < 16) ? gc * 4 : (gc - 16) * 4;
    short8 af[2];
#pragma unroll
    for (int kh = 0; kh < 2; ++kh)
      af[kh] = *reinterpret_cast<const short8*>(&P[(sb + kh * 2 + lh) * 256 + lr * 8]);
    __builtin_amdgcn_s_setprio(1);
#pragma unroll
    for (int kh = 0; kh < 2; ++kh)
      ak = mfma16(af[kh], bc[kh], ak);
    __builtin_amdgcn_s_setprio(0);
  };
  const int gbase = g * 12;
  loadBk(gbase, kb0);
  loadBk(gbase + 1, kb1);
  for (int s = 0; s < 12; s += 3) {
    loadBk(gbase + (s + 2 < 12 ? s + 2 : 11), kb2); mfk(gbase + s, kb0);
    loadBk(gbase + (s + 3 < 12 ? s + 3 : 11), kb0); mfk(gbase + s + 1, kb1);
    loadBk(gbase + (s + 4 < 12 ? s + 4 : 11), kb1); mfk(gbase + s + 2, kb2);
  }
  __syncthreads();                        // all sR/sX reads done
  float* kp = reinterpret_cast<float*>(sR);  // kp[g][32 rows][128 cols]
#pragma unroll
  for (int r = 0; r < 16; ++r) {
    int rr = (r & 3) + 8 * (r >> 2) + 4 * lh;
    kp[g * 4096 + rr * 128 + nw2 * 32 + lr] = ak[r];
  }
  __syncthreads();
  // pass1: per-row sumsq -> scale
  {
    int rr = t >> 4, cg = t & 15;
    float s1 = 0.f;
#pragma unroll
    for (int j = 0; j < 8; ++j) {
      int c = cg * 8 + j;
      float v = kp[rr * 128 + c] + kp[4096 + rr * 128 + c] + keyb[c];
      s1 += v * v;
    }
#pragma unroll
    for (int m = 1; m <= 8; m <<= 1) s1 += __shfl_xor(s1, m);
    if (cg == 0) red[rr] = 1.f / fmaxf(sqrtf(s1), 1e-8f);
  }
  __syncthreads();
  // pass2: column partials of l2norm(k)
  if (t < 128) {
    float p = 0.f;
    float bb = keyb[t];
#pragma unroll 4
    for (int rr = 0; rr < 32; ++rr)
      p += (kp[rr * 128 + t] + kp[4096 + rr * 128 + t] + bb) * red[rr];
    partial[(size_t)blockIdx.x * 128 + t] = p;
  }
}

// ---------------- q reduce (2048 partial blocks, 256 per batch) -------------
__global__ __launch_bounds__(256) void k_qred(const float* __restrict__ partial,
                                              float* __restrict__ q_ws) {
  int gid = blockIdx.x * 256 + threadIdx.x;   // 0..1023
  int b = gid >> 7, c = gid & 127;
  float s = 0.f;
  for (int i = 0; i < 256; ++i) s += partial[(size_t)(b * 256 + i) * 128 + c];
  q_ws[gid] = s * (1.f / 8192.f);
}

// ---------------- cvec = fftn_b @ fftp_w^T (raw fftp) ----------------
__global__ __launch_bounds__(256) void k_cvec(const float* __restrict__ fb,
                                              const float* __restrict__ fftpw,
                                              float* __restrict__ cvec) {
  int o = blockIdx.x * 256 + threadIdx.x;     // 0..511
  const float* w = fftpw + (size_t)o * 512;
  float s = 0.f;
  for (int k = 0; k < 512; ++k) s += fb[k] * w[k];
  cvec[o] = s;
}

// ---------------- memory (episodic + hebbian) ----------------
__global__ __launch_bounds__(256) void k_mem(
    const float* __restrict__ q_ws, const float* __restrict__ mkeys,
    const float* __restrict__ mvals, const float* __restrict__ hebH,
    const float* __restrict__ rmw, const float* __restrict__ rmb,
    const float* __restrict__ mixl, float* __restrict__ hm) {
  const int b = blockIdx.x, t = threadIdx.x;
  __shared__ float qv[128];
  __shared__ float ssim[256];
  __shared__ float red[256];
  __shared__ float tval[8];
  __shared__ int tidx[8];
  __shared__ float wsm[8];
  __shared__ float vcs[128];

  if (t < 128) qv[t] = q_ws[b * 128 + t];
  __syncthreads();
  red[t] = (t < 128) ? qv[t] * qv[t] : 0.f;
  __syncthreads();
  for (int s = 128; s > 0; s >>= 1) {
    if (t < s) red[t] += red[t + s];
    __syncthreads();
  }
  float qsc = 1.f / fmaxf(sqrtf(red[0]), 1e-8f);
  {
    const float* mk = mkeys + ((size_t)b * 256 + t) * 128;
    float dot = 0.f, ms = 0.f;
    for (int k = 0; k < 128; ++k) { float mv = mk[k]; dot += qv[k] * mv; ms += mv * mv; }
    ssim[t] = dot * qsc / fmaxf(sqrtf(ms), 1e-8f);
  }
  __syncthreads();
  for (int it = 0; it < 8; ++it) {
    if (t < 64) {
      float bv = -1e30f; int bi = 0;
#pragma unroll
      for (int u = 0; u < 4; ++u) {
        int m = t * 4 + u;
        float v = ssim[m];
        if (v > bv) { bv = v; bi = m; }
      }
      for (int off = 32; off; off >>= 1) {
        float ov = __shfl_xor(bv, off, 64);
        int oi = __shfl_xor(bi, off, 64);
        if (ov > bv || (ov == bv && oi < bi)) { bv = ov; bi = oi; }
      }
      if (t == 0) { tval[it] = bv; tidx[it] = bi; ssim[bi] = -1e30f; }
    }
    __syncthreads();
  }
  if (t == 0) {
    float m0 = tval[0], sum = 0.f, e[8];
#pragma unroll
    for (int i = 0; i < 8; ++i) { e[i] = expf(tval[i] - m0); sum += e[i]; }
#pragma unroll
    for (int i = 0; i < 8; ++i) wsm[i] = e[i] / sum;
  }
  __syncthreads();
  float mix = 1.f / (1.f + expf(-mixl[0]));
  if (t < 128) {
    float vh = 0.f;
#pragma unroll
    for (int i = 0; i < 8; ++i) vh += wsm[i] * mvals[((size_t)b * 256 + tidx[i]) * 128 + t];
    float vhb = 0.f;
    const float* H = hebH + (size_t)b * 128 * 128;
    for (int k = 0; k < 128; ++k) vhb += qv[k] * H[k * 128 + t];
    vcs[t] = mix * vh + (1.f - mix) * vhb;
  }
  __syncthreads();
  for (int h = t; h < 512; h += 256) {
    float sum = rmb[h];
    const float* wr = rmw + (size_t)h * 128;
    for (int v = 0; v < 128; ++v) sum += vcs[v] * wr[v];
    hm[b * 512 + h] = sum;
  }
}

// ---------------- fused h_tilde -> LN -> fftp GEMM -> hs (BM=32) ------------
// LDS: sX 16K + sR 32K (h_norm overlays) + red 2.5K = 50.5K -> 3 blocks/CU
__global__ __launch_bounds__(512, 4) void k_fused(
    const float* __restrict__ rseq, const float* __restrict__ x,
    const unsigned short* __restrict__ bwp, const unsigned short* __restrict__ uwp,
    const float* __restrict__ ub, const unsigned short* __restrict__ fftps,
    const float* __restrict__ fftpb, const float* __restrict__ fmix,
    const float* __restrict__ cvec, const float* __restrict__ hm,
    float* __restrict__ hs) {
  __shared__ short sX[8192];    // x panel 16KB
  __shared__ short sR[16384];   // r panel 32KB; h_norm overlays after GEMM1
  __shared__ float red[640];
  const int t = threadIdx.x, w = t >> 6, lane = t & 63, lr = lane & 31, lh = lane >> 5;
  const int m0 = blockIdx.x * 32;
  const int bidx = m0 >> 13;

  // ---- stage r panel (8 f4/thread) + x panel (4 f4/thread) ----
#pragma unroll
  for (int i = 0; i < 8; ++i) {
    int c = t + i * 512;                 // 128 float4 per row
    int row = c >> 7, k0 = (c & 127) * 4;
    float4 v = *reinterpret_cast<const float4*>(rseq + (size_t)(m0 + row) * 512 + k0);
    uint2 p;
    p.x = (unsigned)f2bf(v.x) | ((unsigned)f2bf(v.y) << 16);
    p.y = (unsigned)f2bf(v.z) | ((unsigned)f2bf(v.w) << 16);
    *reinterpret_cast<uint2*>(&sR[(k0 >> 3) * 256 + row * 8 + (k0 & 7)]) = p;
  }
#pragma unroll
  for (int i = 0; i < 4; ++i) {
    int c = t + i * 512;
    int row = c >> 6, k0 = (c & 63) * 4;
    float4 v = *reinterpret_cast<const float4*>(x + (size_t)(m0 + row) * 256 + k0);
    uint2 p;
    p.x = (unsigned)f2bf(v.x) | ((unsigned)f2bf(v.y) << 16);
    p.y = (unsigned)f2bf(v.z) | ((unsigned)f2bf(v.w) << 16);
    *reinterpret_cast<uint2*>(&sX[(k0 >> 3) * 256 + row * 8 + (k0 & 7)]) = p;
  }
  barrier_lgkm();

  // ---- GEMM1: h_pre = [r,x] @ [Bw,Uw]^T, 24 barrier-free steps, depth-2 ----
  f32x16 acc[2];
#pragma unroll
  for (int ni = 0; ni < 2; ++ni)
#pragma unroll
    for (int e = 0; e < 16; ++e) acc[ni][e] = 0.f;
  short8 b0[4], b1[4], b2[4];
  auto loadB1 = [&](int s, short8 (&bd)[4]) {
    const unsigned short* wp = (s < 16) ? (bwp + (size_t)s * 16384)
                                        : (uwp + (size_t)(s - 16) * 16384);
#pragma unroll
    for (int kh = 0; kh < 2; ++kh)
#pragma unroll
      for (int ni = 0; ni < 2; ++ni)
        bd[kh * 2 + ni] = *reinterpret_cast<const short8*>(
            wp + (kh * 2 + lh) * 4096 + (64 * w + 32 * ni + lr) * 8);
  };
  auto mf1 = [&](int s, short8 (&bc)[4]) {
    const short* P = (s < 16) ? sR : sX;
    int sb = (s < 16) ? s * 4 : (s - 16) * 4;
    short8 af[2];
#pragma unroll
    for (int kh = 0; kh < 2; ++kh)
      af[kh] = *reinterpret_cast<const short8*>(&P[(sb + kh * 2 + lh) * 256 + lr * 8]);
    __builtin_amdgcn_s_setprio(1);
#pragma unroll
    for (int kh = 0; kh < 2; ++kh)
#pragma unroll
      for (int ni = 0; ni < 2; ++ni)
        acc[ni] = mfma16(af[kh], bc[kh * 2 + ni], acc[ni]);
    __builtin_amdgcn_s_setprio(0);
  };
  loadB1(0, b0);
  loadB1(1, b1);
  for (int s = 0; s < 24; s += 3) {
    loadB1(s + 2 < 24 ? s + 2 : 23, b2); mf1(s, b0);
    loadB1(s + 3 < 24 ? s + 3 : 23, b0); mf1(s + 1, b1);
    loadB1(s + 4 < 24 ? s + 4 : 23, b1); mf1(s + 2, b2);
  }

  // ---- epi1: gelu, LN stats, pack h~, write h_norm into sR ----
#pragma unroll
  for (int ni = 0; ni < 2; ++ni) {
    int col = 64 * w + 32 * ni + lr;
    float ubc = ub[col];
#pragma unroll
    for (int r = 0; r < 16; ++r) {
      float pre = acc[ni][r] + ubc;
      acc[ni][r] = 0.5f * pre * (1.f + erff(pre * 0.70710678118654752f));
    }
  }
#pragma unroll
  for (int r = 0; r < 16; ++r) {
    float s1 = acc[0][r] + acc[1][r];
    float s2 = acc[0][r] * acc[0][r] + acc[1][r] * acc[1][r];
#pragma unroll
    for (int m = 1; m <= 16; m <<= 1) { s1 += __shfl_xor(s1, m); s2 += __shfl_xor(s2, m); }
    int rl = (r & 3) + 8 * (r >> 2) + 4 * lh;
    if (lr == r) { red[w * 32 + rl] = s1; red[256 + w * 32 + rl] = s2; }
  }
  __syncthreads();                         // all GEMM1 sR reads done
  if (t < 32) {
    float s1 = 0.f, s2 = 0.f;
#pragma unroll
    for (int n = 0; n < 8; ++n) { s1 += red[n * 32 + t]; s2 += red[256 + n * 32 + t]; }
    float mean = s1 * (1.f / 512.f);
    float var = s2 * (1.f / 512.f) - mean * mean;
    float rstd = rsqrtf(var + 1e-5f);
    red[512 + t * 2] = mean;
    red[512 + t * 2 + 1] = rstd;
  }
  __syncthreads();
  unsigned htp[2][8];
#pragma unroll
  for (int ni = 0; ni < 2; ++ni)
#pragma unroll
    for (int p = 0; p < 8; ++p)
      htp[ni][p] = (unsigned)f2bf(acc[ni][2 * p]) |
                   ((unsigned)f2bf(acc[ni][2 * p + 1]) << 16);
  auto loadB2 = [&](int s, short8 (&bd)[4]) {
#pragma unroll
    for (int kh = 0; kh < 2; ++kh)
#pragma unroll
      for (int ni = 0; ni < 2; ++ni)
        bd[kh * 2 + ni] = *reinterpret_cast<const short8*>(
            fftps + (size_t)s * 16384 + (kh * 2 + lh) * 4096 + (64 * w + 32 * ni + lr) * 8);
  };
  loadB2(0, b0);                           // prefetch under h_norm writes
  loadB2(1, b1);
#pragma unroll
  for (int q = 0; q < 4; ++q) {
    float4 stA = *reinterpret_cast<float4*>(&red[512 + (8 * q + 4 * lh) * 2]);
    float4 stB = *reinterpret_cast<float4*>(&red[512 + (8 * q + 4 * lh) * 2 + 4]);
    float mean[4] = {stA.x, stA.z, stB.x, stB.z};
    float rstd[4] = {stA.y, stA.w, stB.y, stB.w};
#pragma unroll
    for (int ni = 0; ni < 2; ++ni) {
      int col = 64 * w + 32 * ni + lr;
#pragma unroll
      for (int e = 0; e < 4; ++e) {
        int r = 4 * q + e;
        float z = (acc[ni][r] - mean[e]) * rstd[e];
        int rloc = 8 * q + 4 * lh + e;
        sR[(col >> 3) * 256 + rloc * 8 + (col & 7)] = (short)f2bf(z);
      }
    }
  }
#pragma unroll
  for (int ni = 0; ni < 2; ++ni)
#pragma unroll
    for (int e = 0; e < 16; ++e) acc[ni][e] = 0.f;
  barrier_lgkm();

  // ---- GEMM2: h_norm @ (fftp*g)^T, 16 barrier-free steps, depth-2 ----
  auto mf2 = [&](int s, short8 (&bc)[4]) {
    short8 af[2];
#pragma unroll
    for (int kh = 0; kh < 2; ++kh)
      af[kh] = *reinterpret_cast<const short8*>(&sR[(s * 4 + kh * 2 + lh) * 256 + lr * 8]);
    __builtin_amdgcn_s_setprio(1);
#pragma unroll
    for (int kh = 0; kh < 2; ++kh)
#pragma unroll
      for (int ni = 0; ni < 2; ++ni)
        acc[ni] = mfma16(af[kh], bc[kh * 2 + ni], acc[ni]);
    __builtin_amdgcn_s_setprio(0);
  };
  for (int s = 0; s < 15; s += 3) {
    loadB2(s + 2, b2);                    mf2(s, b0);
    loadB2(s + 3, b0);                    mf2(s + 1, b1);
    loadB2(s + 4 < 16 ? s + 4 : 15, b1);  mf2(s + 2, b2);
  }
  mf2(15, b0);

  // ---- epi2: combine ----
  const float sg = 1.f / (1.f + expf(-fmix[0]));
  const float s2f = sg * sg, oms = 1.f - sg;
#pragma unroll
  for (int ni = 0; ni < 2; ++ni) {
    int col = 64 * w + 32 * ni + lr;
    float base = s2f * cvec[col] + sg * fftpb[col] + 0.5f * hm[bidx * 512 + col];
#pragma unroll
    for (int p = 0; p < 8; ++p) {
      unsigned pk = htp[ni][p];
      int r0 = 2 * p;
      int rloc = (r0 & 3) + 8 * (r0 >> 2) + 4 * lh;
      float o0 = oms * bf2f((unsigned short)(pk & 0xFFFF)) + s2f * acc[ni][r0] + base;
      float o1 = oms * bf2f((unsigned short)(pk >> 16)) + s2f * acc[ni][r0 + 1] + base;
      hs[(size_t)(m0 + rloc) * 512 + col] = o0;
      hs[(size_t)(m0 + rloc + 1) * 512 + col] = o1;
    }
  }
}

extern "C" void kernel_launch(void* const* d_in, const int* in_sizes, int n_in,
                              void* d_out, int out_size, void* d_ws, size_t ws_size,
                              hipStream_t stream) {
  (void)in_sizes; (void)n_in; (void)out_size; (void)ws_size;
  const float* x     = (const float*)d_in[0];
  const float* Wxw   = (const float*)d_in[1];
  const float* Wxb   = (const float*)d_in[2];
  const float* resa  = (const float*)d_in[4];
  const float* Bw    = (const float*)d_in[6];
  const float* Uw    = (const float*)d_in[7];
  const float* Ub    = (const float*)d_in[8];
  const float* fg    = (const float*)d_in[9];
  const float* fb    = (const float*)d_in[10];
  const float* fftpw = (const float*)d_in[11];
  const float* fftpb = (const float*)d_in[12];
  const float* fmix  = (const float*)d_in[13];
  const float* mixl  = (const float*)d_in[14];
  const float* keyw  = (const float*)d_in[15];
  const float* keyb  = (const float*)d_in[16];
  const float* rmw   = (const float*)d_in[19];
  const float* rmb   = (const float*)d_in[20];
  const float* rng   = (const float*)d_in[21];
  const float* rnb   = (const float*)d_in[22];
  const float* mkeys = (const float*)d_in[23];
  const float* mvals = (const float*)d_in[24];
  const float* hebH  = (const float*)d_in[25];

  float* outp = (float*)d_out;
  float* hs   = outp;                               // (B,T,512)
  float* rout = outp + (size_t)65536 * 512;         // (B,T,512)

  unsigned short* wsu = (unsigned short*)d_ws;
  unsigned short* wxp    = wsu;                     // 131072
  unsigned short* keyp   = wsu + 131072;            // 98304
  unsigned short* bwp    = wsu + 229376;            // 262144
  unsigned short* uwp    = wsu + 491520;            // 131072
  unsigned short* fftps  = wsu + 622592;            // 262144
  float* wsf     = (float*)d_ws;
  float* partial = wsf + 524288;                    // 2048*128 = 262144
  float* q_ws    = wsf + 786432;                    // 1024
  float* hm      = wsf + 787456;                    // 4096
  float* cvec    = wsf + 791552;                    // 512

  k_wconv<<<3456, 256, 0, stream>>>(Wxw, keyw, Bw, Uw, fftpw, fg,
                                    wxp, keyp, bwp, uwp, fftps);
  k_cvec <<<2,    256, 0, stream>>>(fb, fftpw, cvec);
  k_rk   <<<2048, 512, 0, stream>>>(x, wxp, keyp, Wxb, resa, rng, rnb, keyb,
                                    rout, partial);
  k_qred <<<4,    256, 0, stream>>>(partial, q_ws);
  k_mem  <<<8,    256, 0, stream>>>(q_ws, mkeys, mvals, hebH, rmw, rmb, mixl, hm);
  k_fused<<<2048, 512, 0, stream>>>(rout, x, bwp, uwp, Ub, fftps, fftpb,
                                    fmix, cvec, hm, hs);
}

// Round 11
// 306.613 us; speedup vs baseline: 1.1138x; 1.0894x over previous
//
#include <hip/hip_runtime.h>
#include <cmath>

// CRSDCell bf16-MFMA pipeline, round 11: round-8 structure (depth-1 prefetch,
// BM=32, 42% occ) + BRANCH-FREE affine addressing in all GEMM loops:
//  - bwp/uwp are contiguous in ws -> single weight pointer, s*16384 stride.
//  - r and x panels contiguous in one LDS array sRX (r slots 0..63, x 64..95)
//    -> A-read address is linear in s; compiler strength-reduces both streams.
//  - k_rk: fused r_seq + k/q partials (split-K k-GEMM, kp overlays sRX).
// FFT folds exactly: irfft(rfft(h)*s) = s*h. h_prev=r_prev=0 kills Wh/A terms.

typedef __attribute__((ext_vector_type(8)))  short short8;
typedef __attribute__((ext_vector_type(16))) float f32x16;

__device__ __forceinline__ unsigned short f2bf(float f) {
  union { float f; unsigned u; } v; v.f = f;
  unsigned r = v.u + 0x7FFF + ((v.u >> 16) & 1);   // RTNE
  return (unsigned short)(r >> 16);
}
__device__ __forceinline__ float bf2f(unsigned short h) {
  union { unsigned u; float f; } v; v.u = ((unsigned)h) << 16; return v.f;
}
__device__ __forceinline__ f32x16 mfma16(short8 a, short8 b, f32x16 c) {
  return __builtin_amdgcn_mfma_f32_32x32x16_bf16(a, b, c, 0, 0, 0);
}
__device__ __forceinline__ void barrier_lgkm() {
  asm volatile("s_waitcnt lgkmcnt(0)" ::: "memory");
  __builtin_amdgcn_s_barrier();
  __builtin_amdgcn_sched_barrier(0);
}

// ---------------- weight convert + pack ----------------
// packed offset for (n,k) in [N][K]: (k>>5)*N*32 + ((k>>3)&3)*N*8 + n*8 + (k&7)
__global__ __launch_bounds__(256) void k_wconv(
    const float* __restrict__ wx, const float* __restrict__ key,
    const float* __restrict__ bw, const float* __restrict__ uw,
    const float* __restrict__ fftpw, const float* __restrict__ fg,
    unsigned short* __restrict__ wxp, unsigned short* __restrict__ keyp,
    unsigned short* __restrict__ bwp, unsigned short* __restrict__ uwp,
    unsigned short* __restrict__ fftps) {
  int i = blockIdx.x * 256 + threadIdx.x;
  if (i >= 884736) return;
  float v; int n, k, N; unsigned short* dst;
  if (i < 131072)      { int j = i;          N = 512; k = j & 255; n = j >> 8; v = wx[j];  dst = wxp; }
  else if (i < 229376) { int j = i - 131072; N = 128; k = j % 768; n = j / 768; v = key[j]; dst = keyp; }
  else if (i < 491520) { int j = i - 229376; N = 512; k = j & 511; n = j >> 9; v = bw[j];  dst = bwp; }
  else if (i < 622592) { int j = i - 491520; N = 512; k = j & 255; n = j >> 8; v = uw[j];  dst = uwp; }
  else                 { int j = i - 622592; N = 512; k = j & 511; n = j >> 9; v = fftpw[j] * fg[k]; dst = fftps; }
  dst[(k >> 5) * (N * 32) + ((k >> 3) & 3) * (N * 8) + n * 8 + (k & 7)] = f2bf(v);
}

// ---------------- K_RK: r_seq + k/q partials (BM=32) ----------------
// LDS: sRX = [r slots 0..63 | x slots 64..95] (48KB), red 2.5KB
__global__ __launch_bounds__(512, 4) void k_rk(
    const float* __restrict__ x, const unsigned short* __restrict__ wxp,
    const unsigned short* __restrict__ keyp,
    const float* __restrict__ wxb, const float* __restrict__ resa,
    const float* __restrict__ rng, const float* __restrict__ rnb,
    const float* __restrict__ keyb,
    float* __restrict__ rout, float* __restrict__ partial) {
  __shared__ short sRX[24576];  // r 32x512 @0, x 32x256 @16384; kp overlays
  __shared__ float red[640];
  const int t = threadIdx.x, w = t >> 6, lane = t & 63, lr = lane & 31, lh = lane >> 5;
  const int m0 = blockIdx.x * 32;

  // ---- stage x panel (slots 64..95) ----
#pragma unroll
  for (int i = 0; i < 4; ++i) {
    int c = t + i * 512;                 // float4 idx; 64 per row
    int row = c >> 6, k0 = (c & 63) * 4;
    float4 v = *reinterpret_cast<const float4*>(x + (size_t)(m0 + row) * 256 + k0);
    uint2 p;
    p.x = (unsigned)f2bf(v.x) | ((unsigned)f2bf(v.y) << 16);
    p.y = (unsigned)f2bf(v.z) | ((unsigned)f2bf(v.w) << 16);
    *reinterpret_cast<uint2*>(&sRX[16384 + (k0 >> 3) * 256 + row * 8 + (k0 & 7)]) = p;
  }
  barrier_lgkm();

  // ---- GEMM0: r_pre = x @ Wx^T, 8 barrier-free steps ----
  f32x16 acc[2];
#pragma unroll
  for (int ni = 0; ni < 2; ++ni)
#pragma unroll
    for (int e = 0; e < 16; ++e) acc[ni][e] = 0.f;
  short8 b0[4], b1[4];
  auto loadB0 = [&](int s, short8 (&bd)[4]) {
#pragma unroll
    for (int kh = 0; kh < 2; ++kh)
#pragma unroll
      for (int ni = 0; ni < 2; ++ni)
        bd[kh * 2 + ni] = *reinterpret_cast<const short8*>(
            wxp + (size_t)s * 16384 + (kh * 2 + lh) * 4096 + (64 * w + 32 * ni + lr) * 8);
  };
  auto mf0 = [&](int s, short8 (&bc)[4]) {
    short8 af[2];
#pragma unroll
    for (int kh = 0; kh < 2; ++kh)
      af[kh] = *reinterpret_cast<const short8*>(
          &sRX[16384 + (s * 4 + kh * 2 + lh) * 256 + lr * 8]);
    __builtin_amdgcn_s_setprio(1);
#pragma unroll
    for (int kh = 0; kh < 2; ++kh)
#pragma unroll
      for (int ni = 0; ni < 2; ++ni)
        acc[ni] = mfma16(af[kh], bc[kh * 2 + ni], acc[ni]);
    __builtin_amdgcn_s_setprio(0);
  };
  loadB0(0, b0);
  for (int s = 0; s < 8; s += 2) {
    loadB0(s + 1, b1);
    mf0(s, b0);
    if (s + 2 < 8) loadB0(s + 2, b0);
    mf0(s + 1, b1);
  }

  // ---- epi0: z=(1-a)tanh(.+b), LN, write rout + r panel ----
#pragma unroll
  for (int ni = 0; ni < 2; ++ni) {
    int col = 64 * w + 32 * ni + lr;
    float al = 1.f / (1.f + expf(-resa[col >> 7]));
    float oma = 1.f - al, bbv = wxb[col];
#pragma unroll
    for (int r = 0; r < 16; ++r)
      acc[ni][r] = oma * tanhf(acc[ni][r] + bbv);
  }
#pragma unroll
  for (int r = 0; r < 16; ++r) {
    float s1 = acc[0][r] + acc[1][r];
    float s2 = acc[0][r] * acc[0][r] + acc[1][r] * acc[1][r];
#pragma unroll
    for (int m = 1; m <= 16; m <<= 1) { s1 += __shfl_xor(s1, m); s2 += __shfl_xor(s2, m); }
    int rl = (r & 3) + 8 * (r >> 2) + 4 * lh;
    if (lr == r) { red[w * 32 + rl] = s1; red[256 + w * 32 + rl] = s2; }
  }
  __syncthreads();
  if (t < 32) {
    float s1 = 0.f, s2 = 0.f;
#pragma unroll
    for (int n = 0; n < 8; ++n) { s1 += red[n * 32 + t]; s2 += red[256 + n * 32 + t]; }
    float mean = s1 * (1.f / 512.f);
    float var = s2 * (1.f / 512.f) - mean * mean;
    float rstd = rsqrtf(var + 1e-5f);
    red[512 + t * 2] = mean;
    red[512 + t * 2 + 1] = rstd;
  }
  __syncthreads();
#pragma unroll
  for (int q = 0; q < 4; ++q) {
    float4 stA = *reinterpret_cast<float4*>(&red[512 + (8 * q + 4 * lh) * 2]);
    float4 stB = *reinterpret_cast<float4*>(&red[512 + (8 * q + 4 * lh) * 2 + 4]);
    float mean[4] = {stA.x, stA.z, stB.x, stB.z};
    float rstd[4] = {stA.y, stA.w, stB.y, stB.w};
#pragma unroll
    for (int ni = 0; ni < 2; ++ni) {
      int col = 64 * w + 32 * ni + lr;
      float g = rng[col], bbv = rnb[col];
#pragma unroll
      for (int e = 0; e < 4; ++e) {
        int r = 4 * q + e;
        int rloc = 8 * q + 4 * lh + e;
        float val = (acc[ni][r] - mean[e]) * rstd[e] * g + bbv;
        rout[(size_t)(m0 + rloc) * 512 + col] = val;
        sRX[(col >> 3) * 256 + rloc * 8 + (col & 7)] = (short)f2bf(val);
      }
    }
  }
  barrier_lgkm();

  // ---- GEMM_k: k = [r,x] @ key^T, split-K over 2 wave-groups ----
  const int g = w >> 2, nw2 = w & 3;     // group, wave-in-group (32 cols each)
  f32x16 ak;
#pragma unroll
  for (int e = 0; e < 16; ++e) ak[e] = 0.f;
  short8 kb0[2], kb1[2];
  auto loadBk = [&](int gc, short8 (&bd)[2]) {
#pragma unroll
    for (int kh = 0; kh < 2; ++kh)
      bd[kh] = *reinterpret_cast<const short8*>(
          keyp + (size_t)gc * 4096 + (kh * 2 + lh) * 1024 + (32 * nw2 + lr) * 8);
  };
  auto mfk = [&](int gc, short8 (&bc)[2]) {
    short8 af[2];
#pragma unroll
    for (int kh = 0; kh < 2; ++kh)
      af[kh] = *reinterpret_cast<const short8*>(
          &sRX[(gc * 4 + kh * 2 + lh) * 256 + lr * 8]);
    __builtin_amdgcn_s_setprio(1);
#pragma unroll
    for (int kh = 0; kh < 2; ++kh)
      ak = mfma16(af[kh], bc[kh], ak);
    __builtin_amdgcn_s_setprio(0);
  };
  const int gbase = g * 12;
  loadBk(gbase, kb0);
  for (int s = 0; s < 12; s += 2) {
    loadBk(gbase + s + 1, kb1);
    mfk(gbase + s, kb0);
    if (s + 2 < 12) loadBk(gbase + s + 2, kb0);
    mfk(gbase + s + 1, kb1);
  }
  __syncthreads();                        // all panel reads done
  float* kp = reinterpret_cast<float*>(sRX);  // kp[g][32 rows][128 cols]
#pragma unroll
  for (int r = 0; r < 16; ++r) {
    int rr = (r & 3) + 8 * (r >> 2) + 4 * lh;
    kp[g * 4096 + rr * 128 + nw2 * 32 + lr] = ak[r];
  }
  __syncthreads();
  // pass1: per-row sumsq -> scale
  {
    int rr = t >> 4, cg = t & 15;
    float s1 = 0.f;
#pragma unroll
    for (int j = 0; j < 8; ++j) {
      int c = cg * 8 + j;
      float v = kp[rr * 128 + c] + kp[4096 + rr * 128 + c] + keyb[c];
      s1 += v * v;
    }
#pragma unroll
    for (int m = 1; m <= 8; m <<= 1) s1 += __shfl_xor(s1, m);
    if (cg == 0) red[rr] = 1.f / fmaxf(sqrtf(s1), 1e-8f);
  }
  __syncthreads();
  // pass2: column partials of l2norm(k)
  if (t < 128) {
    float p = 0.f;
    float bb = keyb[t];
#pragma unroll 4
    for (int rr = 0; rr < 32; ++rr)
      p += (kp[rr * 128 + t] + kp[4096 + rr * 128 + t] + bb) * red[rr];
    partial[(size_t)blockIdx.x * 128 + t] = p;
  }
}

// ---------------- q reduce (2048 partial blocks, 256 per batch) -------------
__global__ __launch_bounds__(256) void k_qred(const float* __restrict__ partial,
                                              float* __restrict__ q_ws) {
  int gid = blockIdx.x * 256 + threadIdx.x;   // 0..1023
  int b = gid >> 7, c = gid & 127;
  float s = 0.f;
  for (int i = 0; i < 256; ++i) s += partial[(size_t)(b * 256 + i) * 128 + c];
  q_ws[gid] = s * (1.f / 8192.f);
}

// ---------------- cvec = fftn_b @ fftp_w^T (raw fftp) ----------------
__global__ __launch_bounds__(256) void k_cvec(const float* __restrict__ fb,
                                              const float* __restrict__ fftpw,
                                              float* __restrict__ cvec) {
  int o = blockIdx.x * 256 + threadIdx.x;     // 0..511
  const float* w = fftpw + (size_t)o * 512;
  float s = 0.f;
  for (int k = 0; k < 512; ++k) s += fb[k] * w[k];
  cvec[o] = s;
}

// ---------------- memory (episodic + hebbian) ----------------
__global__ __launch_bounds__(256) void k_mem(
    const float* __restrict__ q_ws, const float* __restrict__ mkeys,
    const float* __restrict__ mvals, const float* __restrict__ hebH,
    const float* __restrict__ rmw, const float* __restrict__ rmb,
    const float* __restrict__ mixl, float* __restrict__ hm) {
  const int b = blockIdx.x, t = threadIdx.x;
  __shared__ float qv[128];
  __shared__ float ssim[256];
  __shared__ float red[256];
  __shared__ float tval[8];
  __shared__ int tidx[8];
  __shared__ float wsm[8];
  __shared__ float vcs[128];

  if (t < 128) qv[t] = q_ws[b * 128 + t];
  __syncthreads();
  red[t] = (t < 128) ? qv[t] * qv[t] : 0.f;
  __syncthreads();
  for (int s = 128; s > 0; s >>= 1) {
    if (t < s) red[t] += red[t + s];
    __syncthreads();
  }
  float qsc = 1.f / fmaxf(sqrtf(red[0]), 1e-8f);
  {
    const float* mk = mkeys + ((size_t)b * 256 + t) * 128;
    float dot = 0.f, ms = 0.f;
    for (int k = 0; k < 128; ++k) { float mv = mk[k]; dot += qv[k] * mv; ms += mv * mv; }
    ssim[t] = dot * qsc / fmaxf(sqrtf(ms), 1e-8f);
  }
  __syncthreads();
  for (int it = 0; it < 8; ++it) {
    if (t < 64) {
      float bv = -1e30f; int bi = 0;
#pragma unroll
      for (int u = 0; u < 4; ++u) {
        int m = t * 4 + u;
        float v = ssim[m];
        if (v > bv) { bv = v; bi = m; }
      }
      for (int off = 32; off; off >>= 1) {
        float ov = __shfl_xor(bv, off, 64);
        int oi = __shfl_xor(bi, off, 64);
        if (ov > bv || (ov == bv && oi < bi)) { bv = ov; bi = oi; }
      }
      if (t == 0) { tval[it] = bv; tidx[it] = bi; ssim[bi] = -1e30f; }
    }
    __syncthreads();
  }
  if (t == 0) {
    float m0 = tval[0], sum = 0.f, e[8];
#pragma unroll
    for (int i = 0; i < 8; ++i) { e[i] = expf(tval[i] - m0); sum += e[i]; }
#pragma unroll
    for (int i = 0; i < 8; ++i) wsm[i] = e[i] / sum;
  }
  __syncthreads();
  float mix = 1.f / (1.f + expf(-mixl[0]));
  if (t < 128) {
    float vh = 0.f;
#pragma unroll
    for (int i = 0; i < 8; ++i) vh += wsm[i] * mvals[((size_t)b * 256 + tidx[i]) * 128 + t];
    float vhb = 0.f;
    const float* H = hebH + (size_t)b * 128 * 128;
    for (int k = 0; k < 128; ++k) vhb += qv[k] * H[k * 128 + t];
    vcs[t] = mix * vh + (1.f - mix) * vhb;
  }
  __syncthreads();
  for (int h = t; h < 512; h += 256) {
    float sum = rmb[h];
    const float* wr = rmw + (size_t)h * 128;
    for (int v = 0; v < 128; ++v) sum += vcs[v] * wr[v];
    hm[b * 512 + h] = sum;
  }
}

// ---------------- fused h_tilde -> LN -> fftp GEMM -> hs (BM=32) ------------
// LDS: sRX = [r 0..63 | x 64..95] 48KB (h_norm overlays r) + red 2.5K
__global__ __launch_bounds__(512, 4) void k_fused(
    const float* __restrict__ rseq, const float* __restrict__ x,
    const unsigned short* __restrict__ buw,  // bwp; uwp contiguous after it
    const float* __restrict__ ub, const unsigned short* __restrict__ fftps,
    const float* __restrict__ fftpb, const float* __restrict__ fmix,
    const float* __restrict__ cvec, const float* __restrict__ hm,
    float* __restrict__ hs) {
  __shared__ short sRX[24576];  // r 32x512 @0, x 32x256 @16384
  __shared__ float red[640];
  const int t = threadIdx.x, w = t >> 6, lane = t & 63, lr = lane & 31, lh = lane >> 5;
  const int m0 = blockIdx.x * 32;
  const int bidx = m0 >> 13;

  // ---- stage r panel (8 f4/thread) + x panel (4 f4/thread) ----
#pragma unroll
  for (int i = 0; i < 8; ++i) {
    int c = t + i * 512;                 // 128 float4 per row
    int row = c >> 7, k0 = (c & 127) * 4;
    float4 v = *reinterpret_cast<const float4*>(rseq + (size_t)(m0 + row) * 512 + k0);
    uint2 p;
    p.x = (unsigned)f2bf(v.x) | ((unsigned)f2bf(v.y) << 16);
    p.y = (unsigned)f2bf(v.z) | ((unsigned)f2bf(v.w) << 16);
    *reinterpret_cast<uint2*>(&sRX[(k0 >> 3) * 256 + row * 8 + (k0 & 7)]) = p;
  }
#pragma unroll
  for (int i = 0; i < 4; ++i) {
    int c = t + i * 512;
    int row = c >> 6, k0 = (c & 63) * 4;
    float4 v = *reinterpret_cast<const float4*>(x + (size_t)(m0 + row) * 256 + k0);
    uint2 p;
    p.x = (unsigned)f2bf(v.x) | ((unsigned)f2bf(v.y) << 16);
    p.y = (unsigned)f2bf(v.z) | ((unsigned)f2bf(v.w) << 16);
    *reinterpret_cast<uint2*>(&sRX[16384 + (k0 >> 3) * 256 + row * 8 + (k0 & 7)]) = p;
  }
  barrier_lgkm();

  // ---- GEMM1: h_pre = [r,x] @ [Bw,Uw]^T, 24 barrier-free steps ----
  f32x16 acc[2];
#pragma unroll
  for (int ni = 0; ni < 2; ++ni)
#pragma unroll
    for (int e = 0; e < 16; ++e) acc[ni][e] = 0.f;
  short8 b0[4], b1[4];
  auto loadB1 = [&](int s, short8 (&bd)[4]) {
#pragma unroll
    for (int kh = 0; kh < 2; ++kh)
#pragma unroll
      for (int ni = 0; ni < 2; ++ni)
        bd[kh * 2 + ni] = *reinterpret_cast<const short8*>(
            buw + (size_t)s * 16384 + (kh * 2 + lh) * 4096 + (64 * w + 32 * ni + lr) * 8);
  };
  auto mf1 = [&](int s, short8 (&bc)[4]) {
    short8 af[2];
#pragma unroll
    for (int kh = 0; kh < 2; ++kh)
      af[kh] = *reinterpret_cast<const short8*>(
          &sRX[(s * 4 + kh * 2 + lh) * 256 + lr * 8]);
    __builtin_amdgcn_s_setprio(1);
#pragma unroll
    for (int kh = 0; kh < 2; ++kh)
#pragma unroll
      for (int ni = 0; ni < 2; ++ni)
        acc[ni] = mfma16(af[kh], bc[kh * 2 + ni], acc[ni]);
    __builtin_amdgcn_s_setprio(0);
  };
  loadB1(0, b0);
  for (int s = 0; s < 24; s += 2) {
    loadB1(s + 1, b1);
    mf1(s, b0);
    if (s + 2 < 24) loadB1(s + 2, b0);
    mf1(s + 1, b1);
  }

  // ---- epi1: gelu, LN stats, pack h~, write h_norm into r region ----
#pragma unroll
  for (int ni = 0; ni < 2; ++ni) {
    int col = 64 * w + 32 * ni + lr;
    float ubc = ub[col];
#pragma unroll
    for (int r = 0; r < 16; ++r) {
      float pre = acc[ni][r] + ubc;
      acc[ni][r] = 0.5f * pre * (1.f + erff(pre * 0.70710678118654752f));
    }
  }
#pragma unroll
  for (int r = 0; r < 16; ++r) {
    float s1 = acc[0][r] + acc[1][r];
    float s2 = acc[0][r] * acc[0][r] + acc[1][r] * acc[1][r];
#pragma unroll
    for (int m = 1; m <= 16; m <<= 1) { s1 += __shfl_xor(s1, m); s2 += __shfl_xor(s2, m); }
    int rl = (r & 3) + 8 * (r >> 2) + 4 * lh;
    if (lr == r) { red[w * 32 + rl] = s1; red[256 + w * 32 + rl] = s2; }
  }
  __syncthreads();                         // all GEMM1 panel reads done
  if (t < 32) {
    float s1 = 0.f, s2 = 0.f;
#pragma unroll
    for (int n = 0; n < 8; ++n) { s1 += red[n * 32 + t]; s2 += red[256 + n * 32 + t]; }
    float mean = s1 * (1.f / 512.f);
    float var = s2 * (1.f / 512.f) - mean * mean;
    float rstd = rsqrtf(var + 1e-5f);
    red[512 + t * 2] = mean;
    red[512 + t * 2 + 1] = rstd;
  }
  __syncthreads();
  unsigned htp[2][8];
#pragma unroll
  for (int ni = 0; ni < 2; ++ni)
#pragma unroll
    for (int p = 0; p < 8; ++p)
      htp[ni][p] = (unsigned)f2bf(acc[ni][2 * p]) |
                   ((unsigned)f2bf(acc[ni][2 * p + 1]) << 16);
  auto loadB2 = [&](int s, short8 (&bd)[4]) {
#pragma unroll
    for (int kh = 0; kh < 2; ++kh)
#pragma unroll
      for (int ni = 0; ni < 2; ++ni)
        bd[kh * 2 + ni] = *reinterpret_cast<const short8*>(
            fftps + (size_t)s * 16384 + (kh * 2 + lh) * 4096 + (64 * w + 32 * ni + lr) * 8);
  };
  loadB2(0, b0);                           // prefetch under h_norm writes
#pragma unroll
  for (int q = 0; q < 4; ++q) {
    float4 stA = *reinterpret_cast<float4*>(&red[512 + (8 * q + 4 * lh) * 2]);
    float4 stB = *reinterpret_cast<float4*>(&red[512 + (8 * q + 4 * lh) * 2 + 4]);
    float mean[4] = {stA.x, stA.z, stB.x, stB.z};
    float rstd[4] = {stA.y, stA.w, stB.y, stB.w};
#pragma unroll
    for (int ni = 0; ni < 2; ++ni) {
      int col = 64 * w + 32 * ni + lr;
#pragma unroll
      for (int e = 0; e < 4; ++e) {
        int r = 4 * q + e;
        float z = (acc[ni][r] - mean[e]) * rstd[e];
        int rloc = 8 * q + 4 * lh + e;
        sRX[(col >> 3) * 256 + rloc * 8 + (col & 7)] = (short)f2bf(z);
      }
    }
  }
#pragma unroll
  for (int ni = 0; ni < 2; ++ni)
#pragma unroll
    for (int e = 0; e < 16; ++e) acc[ni][e] = 0.f;
  barrier_lgkm();

  // ---- GEMM2: h_norm @ (fftp*g)^T, 16 barrier-free steps ----
  auto mf2 = [&](int s, short8 (&bc)[4]) {
    short8 af[2];
#pragma unroll
    for (int kh = 0; kh < 2; ++kh)
      af[kh] = *reinterpret_cast<const short8*>(
          &sRX[(s * 4 + kh * 2 + lh) * 256 + lr * 8]);
    __builtin_amdgcn_s_setprio(1);
#pragma unroll
    for (int kh = 0; kh < 2; ++kh)
#pragma unroll
      for (int ni = 0; ni < 2; ++ni)
        acc[ni] = mfma16(af[kh], bc[kh * 2 + ni], acc[ni]);
    __builtin_amdgcn_s_setprio(0);
  };
  for (int s = 0; s < 16; s += 2) {
    loadB2(s + 1, b1);
    mf2(s, b0);
    if (s + 2 < 16) loadB2(s + 2, b0);
    mf2(s + 1, b1);
  }

  // ---- epi2: combine ----
  const float sg = 1.f / (1.f + expf(-fmix[0]));
  const float s2f = sg * sg, oms = 1.f - sg;
#pragma unroll
  for (int ni = 0; ni < 2; ++ni) {
    int col = 64 * w + 32 * ni + lr;
    float base = s2f * cvec[col] + sg * fftpb[col] + 0.5f * hm[bidx * 512 + col];
#pragma unroll
    for (int p = 0; p < 8; ++p) {
      unsigned pk = htp[ni][p];
      int r0 = 2 * p;
      int rloc = (r0 & 3) + 8 * (r0 >> 2) + 4 * lh;
      float o0 = oms * bf2f((unsigned short)(pk & 0xFFFF)) + s2f * acc[ni][r0] + base;
      float o1 = oms * bf2f((unsigned short)(pk >> 16)) + s2f * acc[ni][r0 + 1] + base;
      hs[(size_t)(m0 + rloc) * 512 + col] = o0;
      hs[(size_t)(m0 + rloc + 1) * 512 + col] = o1;
    }
  }
}

extern "C" void kernel_launch(void* const* d_in, const int* in_sizes, int n_in,
                              void* d_out, int out_size, void* d_ws, size_t ws_size,
                              hipStream_t stream) {
  (void)in_sizes; (void)n_in; (void)out_size; (void)ws_size;
  const float* x     = (const float*)d_in[0];
  const float* Wxw   = (const float*)d_in[1];
  const float* Wxb   = (const float*)d_in[2];
  const float* resa  = (const float*)d_in[4];
  const float* Bw    = (const float*)d_in[6];
  const float* Uw    = (const float*)d_in[7];
  const float* Ub    = (const float*)d_in[8];
  const float* fg    = (const float*)d_in[9];
  const float* fb    = (const float*)d_in[10];
  const float* fftpw = (const float*)d_in[11];
  const float* fftpb = (const float*)d_in[12];
  const float* fmix  = (const float*)d_in[13];
  const float* mixl  = (const float*)d_in[14];
  const float* keyw  = (const float*)d_in[15];
  const float* keyb  = (const float*)d_in[16];
  const float* rmw   = (const float*)d_in[19];
  const float* rmb   = (const float*)d_in[20];
  const float* rng   = (const float*)d_in[21];
  const float* rnb   = (const float*)d_in[22];
  const float* mkeys = (const float*)d_in[23];
  const float* mvals = (const float*)d_in[24];
  const float* hebH  = (const float*)d_in[25];

  float* outp = (float*)d_out;
  float* hs   = outp;                               // (B,T,512)
  float* rout = outp + (size_t)65536 * 512;         // (B,T,512)

  unsigned short* wsu = (unsigned short*)d_ws;
  unsigned short* wxp    = wsu;                     // 131072
  unsigned short* keyp   = wsu + 131072;            // 98304
  unsigned short* bwp    = wsu + 229376;            // 262144 (uwp contiguous)
  unsigned short* uwp    = wsu + 491520;            // 131072
  unsigned short* fftps  = wsu + 622592;            // 262144
  float* wsf     = (float*)d_ws;
  float* partial = wsf + 524288;                    // 2048*128 = 262144
  float* q_ws    = wsf + 786432;                    // 1024
  float* hm      = wsf + 787456;                    // 4096
  float* cvec    = wsf + 791552;                    // 512

  k_wconv<<<3456, 256, 0, stream>>>(Wxw, keyw, Bw, Uw, fftpw, fg,
                                    wxp, keyp, bwp, uwp, fftps);
  k_cvec <<<2,    256, 0, stream>>>(fb, fftpw, cvec);
  k_rk   <<<2048, 512, 0, stream>>>(x, wxp, keyp, Wxb, resa, rng, rnb, keyb,
                                    rout, partial);
  k_qred <<<4,    256, 0, stream>>>(partial, q_ws);
  k_mem  <<<8,    256, 0, stream>>>(q_ws, mkeys, mvals, hebH, rmw, rmb, mixl, hm);
  k_fused<<<2048, 512, 0, stream>>>(rout, x, bwp, Ub, fftps, fftpb,
                                    fmix, cvec, hm, hs);
}